// Round 1
// baseline (93.284 us; speedup 1.0000x reference)
//
#include <hip/hip_runtime.h>

// out[i] = -sum_k (X[i,k]-mean[k])^2 / scale[0],  N rows, d=64, fp32.
// Memory-bound: 512 MB read + 8 MB write. 16 lanes per row, float4 loads,
// shfl_xor reduce within the 16-lane group.

__global__ void NN_log_den_isotropic_gauss_27281632264837_kernel(
    const float* __restrict__ X,
    const float* __restrict__ mean,
    const float* __restrict__ scale,
    float* __restrict__ out,
    long long N)
{
    const int lane_in_row = threadIdx.x & 15;  // 16 lanes x float4 = 64 floats/row
    const float4 m4 = reinterpret_cast<const float4*>(mean)[lane_in_row];
    const float inv_scale = 1.0f / scale[0];

    const long long rows_per_block = blockDim.x >> 4;               // 16 for 256 threads
    long long row = (long long)blockIdx.x * rows_per_block + (threadIdx.x >> 4);
    const long long stride = (long long)gridDim.x * rows_per_block;

    const float4* __restrict__ X4 = reinterpret_cast<const float4*>(X);

    for (; row < N; row += stride) {
        float4 x4 = X4[row * 16 + lane_in_row];
        float dx = x4.x - m4.x;
        float dy = x4.y - m4.y;
        float dz = x4.z - m4.z;
        float dw = x4.w - m4.w;
        float s = dx * dx + dy * dy + dz * dz + dw * dw;
        // reduce across the 16 lanes of this row (stays within the group)
        s += __shfl_xor(s, 1);
        s += __shfl_xor(s, 2);
        s += __shfl_xor(s, 4);
        s += __shfl_xor(s, 8);
        if (lane_in_row == 0) out[row] = -s * inv_scale;
    }
}

extern "C" void kernel_launch(void* const* d_in, const int* in_sizes, int n_in,
                              void* d_out, int out_size, void* d_ws, size_t ws_size,
                              hipStream_t stream)
{
    const float* X     = (const float*)d_in[0];
    const float* mean  = (const float*)d_in[1];
    const float* scale = (const float*)d_in[2];
    float* out         = (float*)d_out;

    const long long N = (long long)out_size;  // rows; in_sizes[0] == N*64

    const int block = 256;
    const long long rows_per_block = block / 16;
    long long blocks_needed = (N + rows_per_block - 1) / rows_per_block;
    int grid = (int)(blocks_needed < 2048 ? blocks_needed : 2048);  // 256 CU x 8 blocks/CU

    NN_log_den_isotropic_gauss_27281632264837_kernel<<<grid, block, 0, stream>>>(
        X, mean, scale, out, N);
}

// Round 3
// 83.348 us; speedup vs baseline: 1.1192x; 1.1192x over previous
//
#include <hip/hip_runtime.h>

// out[i] = -sum_k (X[i,k]-mean[k])^2 / scale[0],  N rows, d=64, fp32.
// Memory-bound: 512 MB read + 8 MB write.
// 16 lanes per row (f32x4 each); 4 rows per group per iteration for MLP;
// nontemporal loads (X is streamed once, > L3); 32-bit indexing.

typedef float f32x4 __attribute__((ext_vector_type(4)));

__global__ void __launch_bounds__(256, 4)
NN_log_den_isotropic_gauss_27281632264837_kernel(
    const f32x4* __restrict__ X4,
    const float* __restrict__ mean,
    const float* __restrict__ scale,
    float* __restrict__ out,
    unsigned int N)
{
    const unsigned int lane  = threadIdx.x & 15;   // position within row (f32x4 granularity)
    const unsigned int group = threadIdx.x >> 4;   // 16 groups of 16 lanes per block

    const f32x4 m4 = reinterpret_cast<const f32x4*>(mean)[lane];
    const float neg_inv_scale = -1.0f / scale[0];

    // each block-iteration covers 64 rows: group g handles rows base+4g .. base+4g+3
    unsigned int row0   = blockIdx.x * 64u + group * 4u;
    const unsigned int stride = gridDim.x * 64u;

    for (; row0 < N; row0 += stride) {
        if (row0 + 3u < N) {
            const f32x4 a0 = __builtin_nontemporal_load(&X4[(row0 + 0u) * 16u + lane]);
            const f32x4 a1 = __builtin_nontemporal_load(&X4[(row0 + 1u) * 16u + lane]);
            const f32x4 a2 = __builtin_nontemporal_load(&X4[(row0 + 2u) * 16u + lane]);
            const f32x4 a3 = __builtin_nontemporal_load(&X4[(row0 + 3u) * 16u + lane]);

            const f32x4 d0 = a0 - m4;
            const f32x4 d1 = a1 - m4;
            const f32x4 d2 = a2 - m4;
            const f32x4 d3 = a3 - m4;

            float s0 = d0.x*d0.x + d0.y*d0.y + d0.z*d0.z + d0.w*d0.w;
            float s1 = d1.x*d1.x + d1.y*d1.y + d1.z*d1.z + d1.w*d1.w;
            float s2 = d2.x*d2.x + d2.y*d2.y + d2.z*d2.z + d2.w*d2.w;
            float s3 = d3.x*d3.x + d3.y*d3.y + d3.z*d3.z + d3.w*d3.w;

            // four independent 16-lane reduce chains (scheduler interleaves them)
            s0 += __shfl_xor(s0, 1); s1 += __shfl_xor(s1, 1);
            s2 += __shfl_xor(s2, 1); s3 += __shfl_xor(s3, 1);
            s0 += __shfl_xor(s0, 2); s1 += __shfl_xor(s1, 2);
            s2 += __shfl_xor(s2, 2); s3 += __shfl_xor(s3, 2);
            s0 += __shfl_xor(s0, 4); s1 += __shfl_xor(s1, 4);
            s2 += __shfl_xor(s2, 4); s3 += __shfl_xor(s3, 4);
            s0 += __shfl_xor(s0, 8); s1 += __shfl_xor(s1, 8);
            s2 += __shfl_xor(s2, 8); s3 += __shfl_xor(s3, 8);

            if (lane < 4u) {
                float v = (lane == 0u) ? s0 : (lane == 1u) ? s1 : (lane == 2u) ? s2 : s3;
                out[row0 + lane] = v * neg_inv_scale;
            }
        } else {
            // tail: row-at-a-time
            for (unsigned int j = 0; j < 4u; ++j) {
                unsigned int r = row0 + j;
                if (r >= N) break;
                const f32x4 a = X4[r * 16u + lane];
                const f32x4 d = a - m4;
                float s = d.x*d.x + d.y*d.y + d.z*d.z + d.w*d.w;
                s += __shfl_xor(s, 1);
                s += __shfl_xor(s, 2);
                s += __shfl_xor(s, 4);
                s += __shfl_xor(s, 8);
                if (lane == 0u) out[r] = s * neg_inv_scale;
            }
        }
    }
}

extern "C" void kernel_launch(void* const* d_in, const int* in_sizes, int n_in,
                              void* d_out, int out_size, void* d_ws, size_t ws_size,
                              hipStream_t stream)
{
    const f32x4* X4    = (const f32x4*)d_in[0];
    const float* mean  = (const float*)d_in[1];
    const float* scale = (const float*)d_in[2];
    float* out         = (float*)d_out;

    const unsigned int N = (unsigned int)out_size;  // rows

    const int block = 256;
    // 64 rows per block-iteration
    unsigned long long blocks_needed = ((unsigned long long)N + 63ull) / 64ull;
    int grid = (int)(blocks_needed < 2048ull ? blocks_needed : 2048ull);

    NN_log_den_isotropic_gauss_27281632264837_kernel<<<grid, block, 0, stream>>>(
        X4, mean, scale, out, N);
}